// Round 1
// baseline (354.732 us; speedup 1.0000x reference)
//
#include <hip/hip_runtime.h>
#include <math.h>

// Problem constants
#define BSZ 4
#define CCH 8192
#define HH 32
#define WW 32
#define DEMB 256
#define NPOS (BSZ*HH*WW)        // 4096 spatial positions
#define NCHUNK 8
#define CHUNK (CCH/NCHUNK)      // 1024 channels per chunk
#define QSIZE (BSZ*DEMB*HH*WW)  // 1048576
#define KLOFF QSIZE             // kl scalar at this float offset
#define OHOFF (QSIZE+1)         // one_hot starts here (NOT 16B aligned!)

// workspace float-offsets
#define WS_BEST 0
#define WS_IDX  (NCHUNK*NPOS)       // 32768
#define WS_M    (2*NCHUNK*NPOS)     // 65536
#define WS_S    (3*NCHUNK*NPOS)     // 98304
#define WS_SX   (4*NCHUNK*NPOS)     // 131072
#define WS_FIDX (5*NCHUNK*NPOS)     // 163840

// Phase 1: per (b,h,chunk) block — reduce 1024 channels for 32 w-positions.
// Threads: p = tid&7 -> w4 = 4*p (float4 over w), cg = tid>>3 -> 32 channels/iter.
__global__ __launch_bounds__(256) void vq_phase1(const float* __restrict__ x,
                                                 const float* __restrict__ g,
                                                 float* __restrict__ ws) {
    int bid = blockIdx.x;
    int chunk = bid & 7;
    int bh = bid >> 3;      // 0..127
    int b = bh >> 5;
    int h = bh & 31;
    int tid = threadIdx.x;
    int p = tid & 7;
    int cg = tid >> 3;
    int c0 = chunk * CHUNK + cg;
    int w4 = p * 4;
    size_t base = ((size_t)(b * CCH + c0) * (HH * WW)) + h * WW + w4;

    float best[4], m[4], s[4], sx[4];
    int bidx[4];
#pragma unroll
    for (int j = 0; j < 4; j++) { best[j] = -INFINITY; bidx[j] = 0; m[j] = -INFINITY; s[j] = 0.f; sx[j] = 0.f; }

    for (int i = 0; i < CHUNK / 32; i++) {
        size_t idx = base + (size_t)i * 32 * (HH * WW);
        float4 xv = *(const float4*)(x + idx);
        float4 gv = *(const float4*)(g + idx);
        int c = c0 + i * 32;
        float xa[4] = {xv.x, xv.y, xv.z, xv.w};
        float ga[4] = {gv.x, gv.y, gv.z, gv.w};
#pragma unroll
        for (int j = 0; j < 4; j++) {
            float z = xa[j] + ga[j];
            if (z > best[j]) { best[j] = z; bidx[j] = c; }
            float v = xa[j];
            float mn = fmaxf(m[j], v);
            s[j] = s[j] * __expf(m[j] - mn) + __expf(v - mn);
            m[j] = mn;
            sx[j] += v;
        }
    }

    // LDS reduce across cg (32 partials per position), rows padded to 33
    __shared__ float l_best[32][33];
    __shared__ int   l_idx [32][33];
    __shared__ float l_m   [32][33];
    __shared__ float l_s   [32][33];
    __shared__ float l_sx  [32][33];
#pragma unroll
    for (int j = 0; j < 4; j++) {
        l_best[cg][w4 + j] = best[j];
        l_idx [cg][w4 + j] = bidx[j];
        l_m   [cg][w4 + j] = m[j];
        l_s   [cg][w4 + j] = s[j];
        l_sx  [cg][w4 + j] = sx[j];
    }
    __syncthreads();

    if (tid < 32) {
        int w = tid;
        float fb = l_best[0][w]; int fi = l_idx[0][w];
        float fm = l_m[0][w], fs = l_s[0][w], fsx = l_sx[0][w];
        for (int q = 1; q < 32; q++) {
            float v = l_best[q][w]; int ci = l_idx[q][w];
            if (v > fb || (v == fb && ci < fi)) { fb = v; fi = ci; }
            float mm = l_m[q][w], ss = l_s[q][w];
            float mn = fmaxf(fm, mm);
            fs = fs * __expf(fm - mn) + ss * __expf(mm - mn);
            fm = mn;
            fsx += l_sx[q][w];
        }
        int pos = (b * HH + h) * WW + w;
        int o = chunk * NPOS + pos;
        ws[WS_BEST + o] = fb;
        ((int*)ws)[WS_IDX + o] = fi;
        ws[WS_M + o] = fm;
        ws[WS_S + o] = fs;
        ws[WS_SX + o] = fsx;
    }
}

// Phase 2: merge chunks per position; write argmax one-hot 1.0s; kl atomic.
__global__ __launch_bounds__(256) void vq_phase2(float* __restrict__ out,
                                                 float* __restrict__ ws) {
    int pos = blockIdx.x * 256 + threadIdx.x;  // 0..4095
    float fb = -INFINITY; int fi = 0;
    float fm = -INFINITY, fs = 0.f, fsx = 0.f;
    for (int q = 0; q < NCHUNK; q++) {
        int o = q * NPOS + pos;
        float v = ws[WS_BEST + o]; int ci = ((int*)ws)[WS_IDX + o];
        if (v > fb || (v == fb && ci < fi)) { fb = v; fi = ci; }
        float mm = ws[WS_M + o], ss = ws[WS_S + o];
        float mn = fmaxf(fm, mm);
        fs = fs * __expf(fm - mn) + ss * __expf(mm - mn);
        fm = mn;
        fsx += ws[WS_SX + o];
    }
    ((int*)ws)[WS_FIDX + pos] = fi;

    int b = pos >> 10;        // HH*WW = 1024
    int hw = pos & 1023;
    out[OHOFF + (size_t)(b * CCH + fi) * (HH * WW) + hw] = 1.0f;

    float lse = fm + __logf(fs);
    const float logt = -9.0109131783f;  // log(1/8192)
    float term = logt + lse - fsx * (1.0f / (float)CCH);

    // block reduce -> one atomic per block
    for (int off = 32; off > 0; off >>= 1) term += __shfl_down(term, off, 64);
    __shared__ float wsum[4];
    int lane = threadIdx.x & 63, wv = threadIdx.x >> 6;
    if (lane == 0) wsum[wv] = term;
    __syncthreads();
    if (threadIdx.x == 0) {
        float t = wsum[0] + wsum[1] + wsum[2] + wsum[3];
        atomicAdd(out + KLOFF, (0.25f / (float)BSZ) * t);
    }
}

// Phase 3: quantized[b,d,h,w] = emb[idx[b,h,w]][d]; coalesced writes, cached gathers.
__global__ __launch_bounds__(256) void vq_phase3(const float* __restrict__ emb,
                                                 const int* __restrict__ fidx,
                                                 float* __restrict__ outq) {
    int t = blockIdx.x * 256 + threadIdx.x;   // < 1048576
    int b = t >> 18;          // DEMB*HH*WW = 262144
    int r = t & 262143;
    int d = r >> 10;
    int hw = r & 1023;
    int pos = (b << 10) | hw;
    int c = fidx[pos];
    outq[t] = emb[c * DEMB + d];
}

extern "C" void kernel_launch(void* const* d_in, const int* in_sizes, int n_in,
                              void* d_out, int out_size, void* d_ws, size_t ws_size,
                              hipStream_t stream) {
    (void)in_sizes; (void)n_in; (void)out_size; (void)ws_size;
    const float* x   = (const float*)d_in[0];
    const float* emb = (const float*)d_in[1];
    const float* g   = (const float*)d_in[2];
    float* out = (float*)d_out;
    float* ws  = (float*)d_ws;

    // zero kl scalar + whole one_hot region (covers the 0xAA poison)
    hipMemsetAsync(out + KLOFF, 0, (size_t)(1 + (size_t)BSZ * CCH * HH * WW) * sizeof(float), stream);

    vq_phase1<<<dim3(BSZ * HH * NCHUNK), dim3(256), 0, stream>>>(x, g, ws);
    vq_phase2<<<dim3(NPOS / 256), dim3(256), 0, stream>>>(out, ws);
    vq_phase3<<<dim3(QSIZE / 256), dim3(256), 0, stream>>>(emb, (const int*)(ws + WS_FIDX), out);
}